// Round 3
// baseline (68.264 us; speedup 1.0000x reference)
//
#include <hip/hip_runtime.h>

// ForceThresholdCost, round 3 — single fused kernel.
// Algebra (k_c is the all-1000 matrix):
//   w[k]  = 1000 * sum_c (sum_i normals[c,i]) * (sum_j jac[c,j,k])   (k<7)
//   bias  = sum_c forces[c] - sum_k w[k]*start[k]
//   out[n] = (bias + sum_k w[k]*state[n,k]) > 3 ? 10000 : 0
//
// Every WAVE redundantly computes w/bias via a 6-step __shfl_xor fp64
// butterfly (lane = contact c, 64 lanes = C=64): no LDS, no __syncthreads,
// no second launch. Each thread issues its 7 float4 state loads FIRST so the
// preamble (tiny L2-resident loads + shuffles) is hidden under the state
// traffic. fp64 accumulation throughout: output is a discontinuity at fi>3
// (one flip = 10000 absmax), validated absmax==0 in R1/R2.

#define FTC_D 7

__global__ __launch_bounds__(256) void ftc_fused_kernel(
    const float* __restrict__ start_state,   // [7]
    const float* __restrict__ state_batch,   // [ntot*7]
    const float* __restrict__ normals,       // [64*3]
    const float* __restrict__ jac,           // [64*3*7]
    const float* __restrict__ forces,        // [64]
    float* __restrict__ out,                 // [ntot]
    int nquad)                               // ntot/4
{
    const int t = blockIdx.x * 256 + threadIdx.x;

    // ---- issue the big loads first (4 rows = 28 contiguous floats) ----
    float v[28];
    if (t < nquad) {
        const float4* p = (const float4*)(state_batch + (size_t)t * 28);
        float4* vv = (float4*)v;
        #pragma unroll
        for (int j = 0; j < 7; ++j) vv[j] = p[j];
    }

    // ---- per-wave redundant setup: lane = contact c ----
    const int c = threadIdx.x & 63;
    double sn = (double)normals[c * 3 + 0]
              + (double)normals[c * 3 + 1]
              + (double)normals[c * 3 + 2];
    double vals[8];
    #pragma unroll
    for (int k = 0; k < FTC_D; ++k) {
        double tk = (double)jac[c * 21 + 0 * 7 + k]
                  + (double)jac[c * 21 + 1 * 7 + k]
                  + (double)jac[c * 21 + 2 * 7 + k];
        vals[k] = 1000.0 * sn * tk;
    }
    vals[7] = (double)forces[c];

    // 6-step butterfly: afterwards EVERY lane holds the full sums
    #pragma unroll
    for (int off = 32; off > 0; off >>= 1) {
        #pragma unroll
        for (int k = 0; k < 8; ++k)
            vals[k] += __shfl_xor(vals[k], off, 64);
    }

    double bias = vals[7];
    #pragma unroll
    for (int k = 0; k < FTC_D; ++k) bias -= vals[k] * (double)start_state[k];

    // ---- elementwise: 4 rows/thread, fp64 dot, float4 store ----
    if (t < nquad) {
        float4 o;
        float* ov = &o.x;
        #pragma unroll
        for (int r = 0; r < 4; ++r) {
            const float* s = v + r * 7;
            double fi = bias;
            #pragma unroll
            for (int k = 0; k < FTC_D; ++k)
                fi = fma((double)s[k], vals[k], fi);
            ov[r] = (fi > 3.0) ? 10000.0f : 0.0f;
        }
        ((float4*)out)[t] = o;
    }
}

extern "C" void kernel_launch(void* const* d_in, const int* in_sizes, int n_in,
                              void* d_out, int out_size, void* d_ws, size_t ws_size,
                              hipStream_t stream) {
    const float* start_state = (const float*)d_in[0];  // (1,7)
    const float* state_batch = (const float*)d_in[1];  // (N,H,7)
    const float* normals     = (const float*)d_in[2];  // (64,3)
    const float* jac         = (const float*)d_in[3];  // (64,3,7)
    const float* forces      = (const float*)d_in[4];  // (64,)
    float* out = (float*)d_out;

    int ntot  = in_sizes[1] / FTC_D;                   // N*H = 262144
    int nquad = ntot / 4;                              // 65536
    int grid  = (nquad + 255) / 256;                   // 256 blocks -> 1/CU

    ftc_fused_kernel<<<grid, 256, 0, stream>>>(
        start_state, state_batch, normals, jac, forces, out, nquad);
}